// Round 7
// baseline (37.804 us; speedup 1.0000x reference)
//
#include <hip/hip_runtime.h>
#include <hip/hip_bf16.h>
#include <cmath>

// Problem constants
#define BB 128
#define MM 64
#define DD 64
#define PP 1024
#define AN 21
#define NPAIR 2016                      // M*(M-1)/2
#define W1P 68                          // padded LDS row stride (k1)
#define UVP 68                          // padded u/v LDS row stride (k2)

typedef __attribute__((ext_vector_type(8))) short bf16x8;   // 8 bf16 = 4 VGPRs
typedef __attribute__((ext_vector_type(4))) float f32x4;    // MFMA C/D

// tanh-approx GELU via HW transcendentals (~7 VALU + 2 trans).
// max |gelu_tanh - gelu_exact| ~ 5e-4 -> output err ~1e-3, negligible vs
// bf16-MFMA rounding (1.56e-2) and threshold (5.1e-2).
__device__ __forceinline__ float gelu_fast(float x) {
    const float x2 = x * x;
    const float p = fmaf(0.044715f * x2, x, x);        // x + 0.044715 x^3
    const float z = __builtin_amdgcn_exp2f(2.3022150322f * p);  // exp(2c*p)
    const float r = __builtin_amdgcn_rcpf(z + 1.0f);
    const float th = fmaf(-2.0f, r, 1.0f);             // tanh(c*p)
    const float hx = 0.5f * x;
    return fmaf(hx, th, hx);                           // 0.5x(1+tanh)
}

// RNE float -> bf16 bits (values finite)
__device__ __forceinline__ unsigned short f2bf(float x) {
    union { float f; unsigned u; } c; c.f = x;
    unsigned r = c.u + 0x7fffu + ((c.u >> 16) & 1u);
    return (unsigned short)(r >> 16);
}

// pack 2 floats -> 1 u32 of 2 bf16 (emits v_cvt_pk_bf16_f32)
__device__ __forceinline__ unsigned pk2bf(float lo, float hi) {
    __hip_bfloat162 t = __float22bfloat162_rn(make_float2(lo, hi));
    unsigned u; __builtin_memcpy(&u, &t, 4);
    return u;
}

// butterfly sum over each 16-lane row via DPP (xor 1,2,4,8)
__device__ __forceinline__ float row_sum16(float x) {
    int t;
    t = __builtin_amdgcn_update_dpp(0, __float_as_int(x), 0xB1, 0xF, 0xF, true); // xor1
    x += __int_as_float(t);
    t = __builtin_amdgcn_update_dpp(0, __float_as_int(x), 0x4E, 0xF, 0xF, true); // xor2
    x += __int_as_float(t);
    t = __builtin_amdgcn_update_dpp(0, __float_as_int(x), 0x141, 0xF, 0xF, true); // xor4
    x += __int_as_float(t);
    t = __builtin_amdgcn_update_dpp(0, __float_as_int(x), 0x140, 0xF, 0xF, true); // xor8
    x += __int_as_float(t);
    return x;
}

// t -> (i, j), i < j, t = j(j-1)/2 + i
__device__ __forceinline__ void pair_decode(int t, int& i, int& j) {
    int jj = (int)((1.0f + sqrtf(1.0f + 8.0f * (float)t)) * 0.5f);
    if (jj * (jj - 1) / 2 > t) --jj;
    if (jj * (jj + 1) / 2 <= t) ++jj;
    i = t - jj * (jj - 1) / 2;
    j = jj;
}

// ---------------------------------------------------------------------------
// Kernel 1 (FROZEN from round 6 for attribution): u = e@W1[:64]+b1,
// v = e@W1[64:]; W1 transposed+padded in LDS; b1 folded into u; first 16
// blocks emit W2T; zeroes output diagonal. 512 blocks x 256.
// ---------------------------------------------------------------------------
__global__ __launch_bounds__(256) void k_embed_uv(
    const int* __restrict__ positions, const int* __restrict__ amino,
    const float* __restrict__ pos_table, const float* __restrict__ aa_table,
    const float* __restrict__ W1, const float* __restrict__ W2,
    const float* __restrict__ b1,
    float* __restrict__ u, float* __restrict__ v,
    unsigned short* __restrict__ w2t, float* __restrict__ out)
{
    __shared__ __align__(16) float w1u[DD][W1P];
    __shared__ __align__(16) float w1v[DD][W1P];
    __shared__ __align__(16) float es[4][DD];
    const int wave = threadIdx.x >> 6;
    const int lane = threadIdx.x & 63;

    {
        const float4* W14 = (const float4*)W1;
#pragma unroll
        for (int it = 0; it < 8; ++it) {
            const int n = it * 256 + threadIdx.x;
            const int k = n >> 4;
            const int c4 = (n & 15) << 2;
            const float4 w = W14[n];
            if (k < DD) {
                w1u[c4 + 0][k] = w.x; w1u[c4 + 1][k] = w.y;
                w1u[c4 + 2][k] = w.z; w1u[c4 + 3][k] = w.w;
            } else {
                w1v[c4 + 0][k - DD] = w.x; w1v[c4 + 1][k - DD] = w.y;
                w1v[c4 + 2][k - DD] = w.z; w1v[c4 + 3][k - DD] = w.w;
            }
        }
    }
    if (blockIdx.x < 16) {
        const int n = blockIdx.x * 256 + threadIdx.x;
        w2t[(n & 63) * DD + (n >> 6)] = f2bf(W2[n]);
    }
    const float b1l = b1[lane];
    __syncthreads();

#pragma unroll
    for (int tt = 0; tt < 4; ++tt) {
        const int idx = blockIdx.x * 16 + wave * 4 + tt;   // b*M + m
        int p = positions[idx];
        p = p < 0 ? 0 : (p > PP - 1 ? PP - 1 : p);
        int a = amino[idx];
        a = a < 0 ? 0 : (a > AN - 1 ? AN - 1 : a);

        const float e = pos_table[p * DD + lane] + aa_table[a * DD + lane];
        asm volatile("s_waitcnt lgkmcnt(0)" ::: "memory");
        es[wave][lane] = e;
        asm volatile("s_waitcnt lgkmcnt(0)" ::: "memory");

        float uacc = 0.0f, vacc = 0.0f;
#pragma unroll
        for (int k4 = 0; k4 < DD / 4; ++k4) {
            const float4 ek = *(const float4*)&es[wave][k4 * 4];
            const float4 wu = *(const float4*)&w1u[lane][k4 * 4];
            const float4 wv = *(const float4*)&w1v[lane][k4 * 4];
            uacc = fmaf(ek.x, wu.x, uacc); uacc = fmaf(ek.y, wu.y, uacc);
            uacc = fmaf(ek.z, wu.z, uacc); uacc = fmaf(ek.w, wu.w, uacc);
            vacc = fmaf(ek.x, wv.x, vacc); vacc = fmaf(ek.y, wv.y, vacc);
            vacc = fmaf(ek.z, wv.z, vacc); vacc = fmaf(ek.w, wv.w, vacc);
        }
        u[idx * DD + lane] = uacc + b1l;
        v[idx * DD + lane] = vacc;

        if (lane == 0) {
            const int b = idx >> 6, m = idx & 63;
            out[b * MM * MM + m * MM + m] = 0.0f;
        }
    }
}

// ---------------------------------------------------------------------------
// Kernel 2: exact-triangle tiling. Grid (8, 128): WG (q, b) owns pairs
// [q*256, q*256+256) of batch b's linearized upper triangle (2016 pairs
// padded to 2048 slots -> 1.6% waste vs round-6's 21% diagonal waste).
// Stage ALL of u[b], v[b] in LDS (2x 64x68 f32 = 34.8 KB; 4 WG/CU = 139 KB).
// Per wave: 4 tiles of 16 pairs; A-row r -> pair t0+r via closed-form decode;
// u/v both per-lane LDS reads (bank (4*i+koff)%32: distinct rows spread,
// repeats broadcast, max 2-way = free). Layers 2/3 unchanged from round 6.
// ---------------------------------------------------------------------------
__global__ __launch_bounds__(256) void k_pair_mfma(
    const float* __restrict__ u, const float* __restrict__ v,
    const unsigned short* __restrict__ w2t,
    const float* __restrict__ b2, const float* __restrict__ W3,
    const float* __restrict__ b3, float* __restrict__ out)
{
    __shared__ __align__(16) float us[MM][UVP];
    __shared__ __align__(16) float vs[MM][UVP];
    const int lane = threadIdx.x & 63;
    const int wave = threadIdx.x >> 6;
    const int r = lane & 15;        // A row (pair slot) / C col (out feature)
    const int g = lane >> 4;

    const int q8 = blockIdx.x;      // 0..7  : pair-range within batch
    const int b  = blockIdx.y;      // 0..127: batch

    // coalesced stage of full u[b], v[b]: 1024 float4 each over 256 threads
    {
        const float* __restrict__ ub = u + b * (MM * DD);
        const float* __restrict__ vb = v + b * (MM * DD);
#pragma unroll
        for (int it = 0; it < 4; ++it) {
            const int n = it * 256 + threadIdx.x;     // 0..1023
            const int row = n >> 4, qq = (n & 15) * 4;
            *(float4*)&us[row][qq] = *(const float4*)(ub + row * DD + qq);
            *(float4*)&vs[row][qq] = *(const float4*)(vb + row * DD + qq);
        }
    }

    // hoisted per-lane constants (amortized over 4 tiles)
    bf16x8 bfr[2][4];               // B frag: W2[k=kh*32+g*8+e][n=cb*16+r]
#pragma unroll
    for (int kh = 0; kh < 2; ++kh)
#pragma unroll
        for (int cb = 0; cb < 4; ++cb)
            bfr[kh][cb] = *(const bf16x8*)(w2t + ((cb * 16 + r) * DD + kh * 32 + g * 8));
    float b2f[4], w3f[4];
#pragma unroll
    for (int cb = 0; cb < 4; ++cb) {
        b2f[cb] = b2[cb * 16 + r];
        w3f[cb] = W3[cb * 16 + r];
    }
    const float b3s = b3[0];

    __syncthreads();

    float* __restrict__ ob = out + b * (MM * MM);

#pragma unroll
    for (int tt = 0; tt < 4; ++tt) {
        const int t0 = q8 * 256 + wave * 64 + tt * 16;   // first pair of tile
        // ---- decode this lane's pair (clamped; padded slots masked at store) ----
        int tr = t0 + r;
        tr = tr < NPAIR - 1 ? tr : NPAIR - 1;
        int i, j;
        pair_decode(tr, i, j);

        // ---- layer 1: A frags from LDS (both operands per-lane rows) ----
        bf16x8 afr[2];
#pragma unroll
        for (int kh = 0; kh < 2; ++kh) {
            const int koff = kh * 32 + g * 8;
            const float4 u0 = *(const float4*)&us[i][koff];
            const float4 u1 = *(const float4*)&us[i][koff + 4];
            const float4 v0 = *(const float4*)&vs[j][koff];
            const float4 v1 = *(const float4*)&vs[j][koff + 4];
            float x[8];
            x[0] = u0.x + v0.x; x[1] = u0.y + v0.y; x[2] = u0.z + v0.z; x[3] = u0.w + v0.w;
            x[4] = u1.x + v1.x; x[5] = u1.y + v1.y; x[6] = u1.z + v1.z; x[7] = u1.w + v1.w;
            unsigned w0 = pk2bf(gelu_fast(x[0]), gelu_fast(x[1]));
            unsigned w1 = pk2bf(gelu_fast(x[2]), gelu_fast(x[3]));
            unsigned w2 = pk2bf(gelu_fast(x[4]), gelu_fast(x[5]));
            unsigned w3 = pk2bf(gelu_fast(x[6]), gelu_fast(x[7]));
            union { bf16x8 v8; unsigned u4[4]; } cvt;
            cvt.u4[0] = w0; cvt.u4[1] = w1; cvt.u4[2] = w2; cvt.u4[3] = w3;
            afr[kh] = cvt.v8;
        }

        // ---- layer 2: 8 MFMAs ----
        f32x4 acc[4];
#pragma unroll
        for (int cb = 0; cb < 4; ++cb) {
            f32x4 z = {0.0f, 0.0f, 0.0f, 0.0f};
            z = __builtin_amdgcn_mfma_f32_16x16x32_bf16(afr[0], bfr[0][cb], z, 0, 0, 0);
            acc[cb] = __builtin_amdgcn_mfma_f32_16x16x32_bf16(afr[1], bfr[1][cb], z, 0, 0, 0);
        }

        // ---- layer 3: gelu + W3 dot, DPP row-sum over 16-lane group ----
        float s0, s1, s2, s3;
        {
            float a0 = 0, a1 = 0, a2 = 0, a3 = 0;
#pragma unroll
            for (int cb = 0; cb < 4; ++cb) {
                a0 = fmaf(gelu_fast(acc[cb][0] + b2f[cb]), w3f[cb], a0);
                a1 = fmaf(gelu_fast(acc[cb][1] + b2f[cb]), w3f[cb], a1);
                a2 = fmaf(gelu_fast(acc[cb][2] + b2f[cb]), w3f[cb], a2);
                a3 = fmaf(gelu_fast(acc[cb][3] + b2f[cb]), w3f[cb], a3);
            }
            s0 = row_sum16(a0) + b3s;
            s1 = row_sum16(a1) + b3s;
            s2 = row_sum16(a2) + b3s;
            s3 = row_sum16(a3) + b3s;
        }

        // ---- store: lane (g, r<4) owns pair slot p = g*4+r ----
        if (r < 4) {
            const int ts = t0 + g * 4 + r;
            if (ts < NPAIR) {
                int i2, j2;
                pair_decode(ts, i2, j2);
                const float sc = (r == 0) ? s0 : (r == 1) ? s1 : (r == 2) ? s2 : s3;
                ob[i2 * MM + j2] = sc;
                ob[j2 * MM + i2] = sc;
            }
        }
    }
}

extern "C" void kernel_launch(void* const* d_in, const int* in_sizes, int n_in,
                              void* d_out, int out_size, void* d_ws, size_t ws_size,
                              hipStream_t stream) {
    const int*   positions = (const int*)  d_in[0];
    const int*   amino     = (const int*)  d_in[1];
    const float* pos_table = (const float*)d_in[2];
    const float* aa_table  = (const float*)d_in[3];
    const float* W1        = (const float*)d_in[4];
    const float* b1        = (const float*)d_in[5];
    const float* W2        = (const float*)d_in[6];
    const float* b2        = (const float*)d_in[7];
    const float* W3        = (const float*)d_in[8];
    const float* b3        = (const float*)d_in[9];
    float* out = (float*)d_out;

    float* u = (float*)d_ws;                              // [B*M, 64] (2 MB), b1 folded
    float* v = u + (size_t)BB * MM * DD;                  // [B*M, 64] (2 MB)
    unsigned short* w2t = (unsigned short*)(v + (size_t)BB * MM * DD);  // 8 KB bf16

    // K1 (frozen): 8192 tokens, 16/block -> 512 blocks (+ folded w2t prep)
    k_embed_uv<<<512, 256, 0, stream>>>(positions, amino, pos_table, aa_table,
                                        W1, W2, b1, u, v, w2t, out);
    // K2: (8 pair-ranges) x (128 batches), 256 threads, full u/v staged
    k_pair_mfma<<<dim3(8, 128), 256, 0, stream>>>(u, v, w2t, b2, W3, b3, out);
}